// Round 2
// baseline (17002.734 us; speedup 1.0000x reference)
//
#include <hip/hip_runtime.h>
#include <hip/hip_bf16.h>
#include <math.h>

// Round 1 = Round 0 resubmit: previous bench was an infra failure
// ("MI355X container failed twice"), no measurement obtained.

#define B_   32
#define T_   2048
#define IN_  256
#define H_   512
#define O_   512

// ---------------------------------------------------------------------------
// Generic f32 GEMM with bias: C[M,N] = A[M,K] * Bm[K,N] + bias[N]
// Tiles: BM=64, BN=64, BK=32; 256 threads; 4x4 micro-tile per thread.
// M,N,K must be multiples of the tile dims (they are: 65536/512/256/512).
// ---------------------------------------------------------------------------
__global__ __launch_bounds__(256) void gemm_bias_kernel(
    const float* __restrict__ A, const float* __restrict__ Bm,
    const float* __restrict__ bias, float* __restrict__ C,
    int M, int N, int K)
{
    constexpr int BK = 32;
    __shared__ float As[64][33];   // [row][k]  pad 33 to break bank conflicts
    __shared__ float Bs[32][68];   // [k][col]  pad 68: keeps float4 rows 16B-aligned

    const int tid = threadIdx.x;
    const int tx  = tid & 15;      // 16 column-groups (4 cols each)
    const int ty  = tid >> 4;      // 16 row-groups (4 rows each)
    const int bn0 = blockIdx.x * 64;
    const int bm0 = blockIdx.y * 64;

    float acc[4][4] = {};

    for (int kk = 0; kk < K; kk += BK) {
        // Stage A tile 64x32 (8 elements/thread, coalesced rows)
        #pragma unroll
        for (int i = 0; i < 8; ++i) {
            int idx = tid + i * 256;
            int r = idx >> 5, k = idx & 31;
            As[r][k] = A[(size_t)(bm0 + r) * K + kk + k];
        }
        // Stage B tile 32x64 (8 elements/thread, coalesced rows)
        #pragma unroll
        for (int i = 0; i < 8; ++i) {
            int idx = tid + i * 256;
            int k = idx >> 6, c = idx & 63;
            Bs[k][c] = Bm[(size_t)(kk + k) * N + bn0 + c];
        }
        __syncthreads();

        #pragma unroll
        for (int k = 0; k < BK; ++k) {
            float a0 = As[ty * 4 + 0][k];
            float a1 = As[ty * 4 + 1][k];
            float a2 = As[ty * 4 + 2][k];
            float a3 = As[ty * 4 + 3][k];
            float4 b4 = *reinterpret_cast<const float4*>(&Bs[k][tx * 4]);
            acc[0][0] += a0 * b4.x; acc[0][1] += a0 * b4.y; acc[0][2] += a0 * b4.z; acc[0][3] += a0 * b4.w;
            acc[1][0] += a1 * b4.x; acc[1][1] += a1 * b4.y; acc[1][2] += a1 * b4.z; acc[1][3] += a1 * b4.w;
            acc[2][0] += a2 * b4.x; acc[2][1] += a2 * b4.y; acc[2][2] += a2 * b4.z; acc[2][3] += a2 * b4.w;
            acc[3][0] += a3 * b4.x; acc[3][1] += a3 * b4.y; acc[3][2] += a3 * b4.z; acc[3][3] += a3 * b4.w;
        }
        __syncthreads();
    }

    const float4 bv = *reinterpret_cast<const float4*>(&bias[bn0 + tx * 4]);
    #pragma unroll
    for (int i = 0; i < 4; ++i) {
        float4 o;
        o.x = acc[i][0] + bv.x;
        o.y = acc[i][1] + bv.y;
        o.z = acc[i][2] + bv.z;
        o.w = acc[i][3] + bv.w;
        *reinterpret_cast<float4*>(&C[(size_t)(bm0 + ty * 4 + i) * N + bn0 + tx * 4]) = o;
    }
}

// ---------------------------------------------------------------------------
// Recurrence: one block per batch row b (32 blocks, 1024 threads = 16 waves).
//   h_t = tanh(xp[b,t,:] + h_{t-1} @ W_hid)   (W_hid streamed from L2 each step)
// Decomposition per thread: jg = 4 output columns, kg = 64-element k-slice.
//   128 j-groups x 8 k-groups = 1024 threads; 256 FMA/thread/step.
// h lives in LDS; k-slice reads are wave-uniform float4 broadcasts.
// ---------------------------------------------------------------------------
__global__ __launch_bounds__(1024) void rnn_recur_kernel(
    const float* __restrict__ xp,   // [B,T,H]  (x@W_in + b_hid)
    const float* __restrict__ h0,   // [B,H]
    const float* __restrict__ Wh,   // [H,H] row-major: Wh[k*H + j]
    float* __restrict__ hs)         // [B,T,H]
{
    __shared__ __align__(16) float h_lds[H_];
    __shared__ __align__(16) float part[8][H_];

    const int b   = blockIdx.x;
    const int tid = threadIdx.x;
    const int jg  = tid & 127;   // column group: columns jg*4 .. jg*4+3
    const int kg  = tid >> 7;    // k group: k in [kg*64, kg*64+64)

    if (tid < H_) h_lds[tid] = h0[b * H_ + tid];
    __syncthreads();

    const float4* __restrict__ Wv = reinterpret_cast<const float4*>(Wh); // [k][jg] : k*128 + jg
    const float*  __restrict__ xpb = xp + (size_t)b * T_ * H_;
    float*        __restrict__ hsb = hs + (size_t)b * T_ * H_;

    for (int t = 0; t < T_; ++t) {
        float ax = 0.f, ay = 0.f, az = 0.f, aw = 0.f;
        const float4* h4p = reinterpret_cast<const float4*>(&h_lds[kg * 64]);
        const int kbase = kg * 64;
        #pragma unroll 4
        for (int k04 = 0; k04 < 16; ++k04) {
            float4 h4 = h4p[k04];                 // wave-uniform LDS broadcast
            int kb = kbase + k04 * 4;
            float4 w0 = Wv[(kb + 0) * 128 + jg];  // 16B/lane, 1KB contiguous per wave
            float4 w1 = Wv[(kb + 1) * 128 + jg];
            float4 w2 = Wv[(kb + 2) * 128 + jg];
            float4 w3 = Wv[(kb + 3) * 128 + jg];
            ax += h4.x * w0.x + h4.y * w1.x + h4.z * w2.x + h4.w * w3.x;
            ay += h4.x * w0.y + h4.y * w1.y + h4.z * w2.y + h4.w * w3.y;
            az += h4.x * w0.z + h4.y * w1.z + h4.z * w2.z + h4.w * w3.z;
            aw += h4.x * w0.w + h4.y * w1.w + h4.z * w2.w + h4.w * w3.w;
        }
        float4 accv; accv.x = ax; accv.y = ay; accv.z = az; accv.w = aw;
        *reinterpret_cast<float4*>(&part[kg][jg * 4]) = accv;
        __syncthreads();

        if (tid < H_) {
            float s = xpb[(size_t)t * H_ + tid];
            #pragma unroll
            for (int g = 0; g < 8; ++g) s += part[g][tid];
            float hv = tanhf(s);
            h_lds[tid] = hv;                       // safe: all reads done at barrier
            hsb[(size_t)t * H_ + tid] = hv;
        }
        __syncthreads();
    }
}

// ---------------------------------------------------------------------------
extern "C" void kernel_launch(void* const* d_in, const int* in_sizes, int n_in,
                              void* d_out, int out_size, void* d_ws, size_t ws_size,
                              hipStream_t stream)
{
    const float* x    = (const float*)d_in[0];  // [32,2048,256]
    const float* h0   = (const float*)d_in[1];  // [32,512]
    // d_in[2] = c : unused by the reference math
    const float* Win  = (const float*)d_in[3];  // [256,512]
    const float* Whid = (const float*)d_in[4];  // [512,512]
    const float* bhid = (const float*)d_in[5];  // [512]
    const float* Wout = (const float*)d_in[6];  // [512,512]
    const float* bout = (const float*)d_in[7];  // [512]

    float* hs    = (float*)d_out;                          // [32,2048,512]
    float* outs  = (float*)d_out + (size_t)B_ * T_ * H_;   // [32,2048,512]
    float* xproj = outs;  // stage x@W_in+b_hid in the outs region (same size),
                          // consumed by the recurrence, then overwritten below.

    const int M = B_ * T_;            // 65536
    dim3 blk(256);
    dim3 grid_gemm(H_ / 64, M / 64);  // (8, 1024)

    // 1) x_proj = x @ W_in + b_hid        [65536,256]x[256,512]
    gemm_bias_kernel<<<grid_gemm, blk, 0, stream>>>(x, Win, bhid, xproj, M, H_, IN_);

    // 2) sequential recurrence -> hs
    rnn_recur_kernel<<<dim3(B_), dim3(1024), 0, stream>>>(xproj, h0, Whid, hs);

    // 3) outs = hs @ W_out + b_out        [65536,512]x[512,512]  (overwrites xproj)
    gemm_bias_kernel<<<grid_gemm, blk, 0, stream>>>(hs, Wout, bout, outs, M, O_, H_);
}